// Round 7
// baseline (347.446 us; speedup 1.0000x reference)
//
#include <hip/hip_runtime.h>
#include <hip/hip_bf16.h>
#include <cstdint>

#define DIMC 192
#define BB 4
#define NN 16384
#define D3 576
#define CHD 48
#define WWID 128
#define HHGT 128
#define NCK 64          // score chunks
#define CKW 256         // cols per score chunk

typedef short short8 __attribute__((ext_vector_type(8)));
typedef float f32x4 __attribute__((ext_vector_type(4)));

union FragU { uint4 u4; short8 s8; };

// ---------- bf16 helpers ----------
__device__ __forceinline__ float bf2f(uint16_t v) {
    return __uint_as_float(((uint32_t)v) << 16);
}
__device__ __forceinline__ float2 upk2(uint32_t u) {
    float2 r;
    r.x = __uint_as_float(u << 16);
    r.y = __uint_as_float(u & 0xffff0000u);
    return r;
}
__device__ __forceinline__ uint16_t f2bf(float f) {
    uint32_t x = __float_as_uint(f);
    return (uint16_t)((x + 0x7fffu + ((x >> 16) & 1u)) >> 16);
}
__device__ __forceinline__ uint4 pack8(const uint16_t* v) {
    uint4 u;
    u.x = (uint32_t)v[0] | ((uint32_t)v[1] << 16);
    u.y = (uint32_t)v[2] | ((uint32_t)v[3] << 16);
    u.z = (uint32_t)v[4] | ((uint32_t)v[5] << 16);
    u.w = (uint32_t)v[6] | ((uint32_t)v[7] << 16);
    return u;
}
__device__ __forceinline__ uint4 packf8(float4 lo, float4 hi) {
    uint16_t vv[8] = {f2bf(lo.x), f2bf(lo.y), f2bf(lo.z), f2bf(lo.w),
                      f2bf(hi.x), f2bf(hi.y), f2bf(hi.z), f2bf(hi.w)};
    return pack8(vv);
}

// ---------- merged qkv conv1x1 MFMA (ms + sar in one launch) ----------
// grid 1024: path = bid>>9 (0=ms->tmp, 1=sar->tmp2); W converted fp32->bf16 inline.
__global__ __launch_bounds__(256, 2) void k_conv_both(
    const float* __restrict__ ms, const float* __restrict__ sarp,
    const float* __restrict__ w_ms, const float* __restrict__ w_sar,
    const float* __restrict__ b_ms, const float* __restrict__ b_sar,
    uint16_t* __restrict__ out_ms, uint16_t* __restrict__ out_sar)
{
    __shared__ uint16_t xs[128][200];   // [n][k]; reused as store scratch later
    __shared__ uint16_t wst[64][200];   // [m][k]
    const int t = threadIdx.x;
    const int bid = blockIdx.x;
    const int path = bid >> 9;
    const int rem = bid & 511;
    const int nb = rem & 127;
    const int b = rem >> 7;
    const int n0 = nb * 128;

    const float* x      = path ? sarp  : ms;
    const float* wsrc   = path ? w_sar : w_ms;
    const float* bias   = path ? b_sar : b_ms;
    uint16_t* out       = path ? out_sar : out_ms;

    const int lane = t & 63, wvid = t >> 6;
    const int lm = lane & 15, g = lane >> 4;
    const int wm = wvid >> 1, wn = wvid & 1;
    const int wm_ = t >> 2, wq = t & 3;

    // ---- stage X once: fp32 -> bf16, transposed to [n][k] ----
    {
        const int sn = t & 127, kh = t >> 7;
        const float* xcol = x + ((size_t)b * DIMC + kh * 96) * NN + n0 + sn;
        for (int u = 0; u < 12; ++u) {
            uint16_t vals[8];
#pragma unroll
            for (int j = 0; j < 8; ++j)
                vals[j] = f2bf(xcol[(size_t)(u * 8 + j) * NN]);
            *(uint4*)&xs[sn][(kh * 12 + u) * 8] = pack8(vals);
        }
    }
    // ---- stage W m-block 0 (fp32 -> bf16 inline) ----
    {
        const float* wrow = wsrc + (size_t)wm_ * DIMC;
#pragma unroll
        for (int i = 0; i < 6; ++i) {
            const int unit = i * 4 + wq;
            float4 lo = *(const float4*)&wrow[unit * 8];
            float4 hi = *(const float4*)&wrow[unit * 8 + 4];
            *(uint4*)&wst[wm_][unit * 8] = packf8(lo, hi);
        }
    }
    __syncthreads();

    // ---- hoist B fragments (reused across all 9 m-blocks) ----
    FragU bfr[6][4];
#pragma unroll
    for (int ks = 0; ks < 6; ++ks)
#pragma unroll
        for (int nj = 0; nj < 4; ++nj) {
            const int row = wn * 64 + nj * 16 + lm;
            bfr[ks][nj].u4 = *(const uint4*)&xs[row][ks * 32 + g * 8];
        }
    __syncthreads();   // all waves done reading xs -> safe to reuse as scratch

    uint16_t* sw = &xs[0][0] + wvid * (32 * 72);  // wave-private 32x72 u16

    for (int mb = 0; mb < 9; ++mb) {
        if (mb) {
            __syncthreads();
            const float* wrow = wsrc + (size_t)(mb * 64 + wm_) * DIMC;
#pragma unroll
            for (int i = 0; i < 6; ++i) {
                const int unit = i * 4 + wq;
                float4 lo = *(const float4*)&wrow[unit * 8];
                float4 hi = *(const float4*)&wrow[unit * 8 + 4];
                *(uint4*)&wst[wm_][unit * 8] = packf8(lo, hi);
            }
            __syncthreads();
        }
        f32x4 acc[2][4];
#pragma unroll
        for (int mi = 0; mi < 2; ++mi)
#pragma unroll
            for (int nj = 0; nj < 4; ++nj) acc[mi][nj] = (f32x4){0.f, 0.f, 0.f, 0.f};
#pragma unroll
        for (int ks = 0; ks < 6; ++ks) {
            FragU afr[2];
#pragma unroll
            for (int mi = 0; mi < 2; ++mi) {
                const int row = wm * 32 + mi * 16 + lm;
                afr[mi].u4 = *(const uint4*)&wst[row][ks * 32 + g * 8];
            }
#pragma unroll
            for (int mi = 0; mi < 2; ++mi)
#pragma unroll
                for (int nj = 0; nj < 4; ++nj)
                    acc[mi][nj] = __builtin_amdgcn_mfma_f32_16x16x32_bf16(
                        afr[mi].s8, bfr[ks][nj].s8, acc[mi][nj], 0, 0, 0);
        }
        // ---- epilogue: acc -> wave-private LDS -> coalesced 16B stores ----
#pragma unroll
        for (int mi = 0; mi < 2; ++mi) {
            const int rbase = mb * 64 + wm * 32 + mi * 16 + g * 4;
            const float4 bv = *(const float4*)&bias[rbase];
            const float bva[4] = {bv.x, bv.y, bv.z, bv.w};
#pragma unroll
            for (int nj = 0; nj < 4; ++nj)
#pragma unroll
                for (int r = 0; r < 4; ++r)
                    sw[(mi * 16 + g * 4 + r) * 72 + nj * 16 + lm] =
                        f2bf(acc[mi][nj][r] + bva[r]);
        }
        const int l8 = lane & 7, r8 = lane >> 3;
#pragma unroll
        for (int pass = 0; pass < 4; ++pass) {
            const int rr = pass * 8 + r8;
            uint4 v = *(const uint4*)&sw[rr * 72 + l8 * 8];
            const int grow = mb * 64 + wm * 32 + rr;
            *(uint4*)&out[((size_t)b * D3 + grow) * NN + n0 + wn * 64 + l8 * 8] = v;
        }
    }
}

// ---------- merged proj MFMA (sar: 1 phase; ms: 2 phases w/ folded weights) ----------
// grid 1024: path = bid>>9 (0=sar, 1=ms).
// ms: out = (Wa+Wb)@ms_self + Wb@cross + bias + resid  (fold done in W staging)
__global__ __launch_bounds__(256, 2) void k_proj_both(
    const uint16_t* __restrict__ sar_self, const uint16_t* __restrict__ ms_self,
    const uint16_t* __restrict__ crossb,
    const float* __restrict__ w_sar, const float* __restrict__ w_ms,
    const float* __restrict__ b_sar, const float* __restrict__ b_ms,
    const float* __restrict__ resid_sar, const float* __restrict__ resid_ms,
    float* __restrict__ out_sar, float* __restrict__ out_ms)
{
    __shared__ uint16_t xs[128][200];
    __shared__ uint16_t wst[64][200];
    const int t = threadIdx.x;
    const int bid = blockIdx.x;
    const int path = bid >> 9;          // 0=sar 1=ms
    const int rem = bid & 511;
    const int nb = rem & 127;
    const int b = rem >> 7;
    const int n0 = nb * 128;
    const int nph = path ? 2 : 1;

    const float* bias  = path ? b_ms : b_sar;
    const float* resid = path ? resid_ms : resid_sar;
    float* out         = path ? out_ms : out_sar;

    const int lane = t & 63, wvid = t >> 6;
    const int lm = lane & 15, g = lane >> 4;
    const int wm = wvid >> 1, wn = wvid & 1;
    const int wm_ = t >> 2, wq = t & 3;

    f32x4 acc[3][2][4];
#pragma unroll
    for (int mb = 0; mb < 3; ++mb)
#pragma unroll
        for (int mi = 0; mi < 2; ++mi)
#pragma unroll
            for (int nj = 0; nj < 4; ++nj) acc[mb][mi][nj] = (f32x4){0.f, 0.f, 0.f, 0.f};

    for (int ph = 0; ph < nph; ++ph) {
        const uint16_t* xsrc = path ? (ph ? crossb : ms_self) : sar_self;
        if (ph) __syncthreads();
        // stage X (bf16, transpose to [n][k])
        {
            const int sn = t & 127, kh = t >> 7;
            const uint16_t* xcol = xsrc + ((size_t)b * DIMC + kh * 96) * NN + n0 + sn;
            for (int u = 0; u < 12; ++u) {
                uint16_t vals[8];
#pragma unroll
                for (int j = 0; j < 8; ++j)
                    vals[j] = xcol[(size_t)(u * 8 + j) * NN];
                *(uint4*)&xs[sn][(kh * 12 + u) * 8] = pack8(vals);
            }
        }
        // stage W m-block 0 (fp32 -> bf16 inline, fold for ms ph0)
        {
            const float* wrow = path
                ? w_ms + (size_t)wm_ * 384 + (ph ? 192 : 0)
                : w_sar + (size_t)wm_ * DIMC;
            const bool addb = path && (ph == 0);
#pragma unroll
            for (int i = 0; i < 6; ++i) {
                const int unit = i * 4 + wq;
                float4 lo = *(const float4*)&wrow[unit * 8];
                float4 hi = *(const float4*)&wrow[unit * 8 + 4];
                if (addb) {
                    float4 lo2 = *(const float4*)&wrow[192 + unit * 8];
                    float4 hi2 = *(const float4*)&wrow[192 + unit * 8 + 4];
                    lo.x += lo2.x; lo.y += lo2.y; lo.z += lo2.z; lo.w += lo2.w;
                    hi.x += hi2.x; hi.y += hi2.y; hi.z += hi2.z; hi.w += hi2.w;
                }
                *(uint4*)&wst[wm_][unit * 8] = packf8(lo, hi);
            }
        }
        __syncthreads();
        FragU bfr[6][4];
#pragma unroll
        for (int ks = 0; ks < 6; ++ks)
#pragma unroll
            for (int nj = 0; nj < 4; ++nj) {
                const int row = wn * 64 + nj * 16 + lm;
                bfr[ks][nj].u4 = *(const uint4*)&xs[row][ks * 32 + g * 8];
            }
        for (int mb = 0; mb < 3; ++mb) {
            if (mb) {
                __syncthreads();
                const float* wrow = path
                    ? w_ms + (size_t)(mb * 64 + wm_) * 384 + (ph ? 192 : 0)
                    : w_sar + (size_t)(mb * 64 + wm_) * DIMC;
                const bool addb = path && (ph == 0);
#pragma unroll
                for (int i = 0; i < 6; ++i) {
                    const int unit = i * 4 + wq;
                    float4 lo = *(const float4*)&wrow[unit * 8];
                    float4 hi = *(const float4*)&wrow[unit * 8 + 4];
                    if (addb) {
                        float4 lo2 = *(const float4*)&wrow[192 + unit * 8];
                        float4 hi2 = *(const float4*)&wrow[192 + unit * 8 + 4];
                        lo.x += lo2.x; lo.y += lo2.y; lo.z += lo2.z; lo.w += lo2.w;
                        hi.x += hi2.x; hi.y += hi2.y; hi.z += hi2.z; hi.w += hi2.w;
                    }
                    *(uint4*)&wst[wm_][unit * 8] = packf8(lo, hi);
                }
                __syncthreads();
            }
#pragma unroll
            for (int ks = 0; ks < 6; ++ks) {
                FragU afr[2];
#pragma unroll
                for (int mi = 0; mi < 2; ++mi) {
                    const int row = wm * 32 + mi * 16 + lm;
                    afr[mi].u4 = *(const uint4*)&wst[row][ks * 32 + g * 8];
                }
#pragma unroll
                for (int mi = 0; mi < 2; ++mi)
#pragma unroll
                    for (int nj = 0; nj < 4; ++nj)
                        acc[mb][mi][nj] = __builtin_amdgcn_mfma_f32_16x16x32_bf16(
                            afr[mi].s8, bfr[ks][nj].s8, acc[mb][mi][nj], 0, 0, 0);
            }
        }
    }
    // epilogue: bias + residual, fp32 out
#pragma unroll
    for (int mb = 0; mb < 3; ++mb)
#pragma unroll
        for (int mi = 0; mi < 2; ++mi) {
            const int rbase = mb * 64 + wm * 32 + mi * 16 + g * 4;
            const float4 bv = *(const float4*)&bias[rbase];
            const float bva[4] = {bv.x, bv.y, bv.z, bv.w};
#pragma unroll
            for (int nj = 0; nj < 4; ++nj) {
                const int gcol = n0 + wn * 64 + nj * 16 + lm;
#pragma unroll
                for (int r = 0; r < 4; ++r) {
                    const size_t idx = ((size_t)b * DIMC + rbase + r) * NN + gcol;
                    out[idx] = resid[idx] + acc[mb][mi][nj][r] + bva[r];
                }
            }
        }
}

// ---------- merged depthwise 3x3 + bias (ms + sar), 8 px/thread ----------
__global__ __launch_bounds__(256) void k_dw_both(
    const uint16_t* __restrict__ in0, const uint16_t* __restrict__ in1,
    const float* __restrict__ w_ms, const float* __restrict__ w_sar,
    const float* __restrict__ b_ms, const float* __restrict__ b_sar,
    uint16_t* __restrict__ out0, uint16_t* __restrict__ out1)
{
    const int t = threadIdx.x;
    int bc = blockIdx.z;
    const int path = (bc >= BB * D3);
    if (path) bc -= BB * D3;
    const int ch = bc % D3;
    const uint16_t* in = path ? in1 : in0;
    const float* w9    = path ? w_sar : w_ms;
    const float* bias  = path ? b_sar : b_ms;
    uint16_t* out      = path ? out1 : out0;

    const int xg = t & 15, yl = t >> 4;
    const int x0 = xg * 8;
    const int y = blockIdx.y * 16 + yl;
    const uint16_t* p = in + (size_t)bc * NN;
    float wv[9];
#pragma unroll
    for (int k = 0; k < 9; ++k) wv[k] = w9[ch * 9 + k];
    float r[3][10];
#pragma unroll
    for (int dy = 0; dy < 3; ++dy) {
        const int yy = y + dy - 1;
        if (yy < 0 || yy >= HHGT) {
#pragma unroll
            for (int j = 0; j < 10; ++j) r[dy][j] = 0.f;
        } else {
            const uint16_t* row = p + yy * WWID;
            uint4 u = *(const uint4*)(row + x0);
            const uint16_t* pv = (const uint16_t*)&u;
#pragma unroll
            for (int j = 0; j < 8; ++j) r[dy][j + 1] = bf2f(pv[j]);
            r[dy][0] = (x0 > 0) ? bf2f(row[x0 - 1]) : 0.f;
            r[dy][9] = (x0 + 8 < WWID) ? bf2f(row[x0 + 8]) : 0.f;
        }
    }
    const float base = bias[ch];
    uint16_t ov[8];
#pragma unroll
    for (int j = 0; j < 8; ++j) {
        float a = base;
#pragma unroll
        for (int dy = 0; dy < 3; ++dy)
#pragma unroll
            for (int dx = 0; dx < 3; ++dx)
                a = fmaf(r[dy][j + dx], wv[dy * 3 + dx], a);
        ov[j] = f2bf(a);
    }
    *(uint4*)(out + (size_t)bc * NN + y * WWID + x0) = pack8(ov);
}

// ---------- MFMA scores + fused norm partials (NCK chunks) ----------
__global__ __launch_bounds__(256) void k_scores_mfma(
    const uint16_t* __restrict__ qkv_ms, const uint16_t* __restrict__ qkv_sar,
    float* __restrict__ partial, float* __restrict__ sumsq)
{
    const int t = threadIdx.x;
    const int bid = blockIdx.x;
    const int ck = bid & (NCK - 1);
    const int pid = bid / NCK;         // b*4 + h
    const int h = pid & 3, b = pid >> 2;
    const int n0 = ck * CKW;
    const int lane = t & 63, w = t >> 6;

    const uint16_t* qm  = qkv_ms  + ((size_t)b * D3 + h * CHD) * NN;
    const uint16_t* km  = qkv_ms  + ((size_t)b * D3 + DIMC + h * CHD) * NN;
    const uint16_t* qsr = qkv_sar + ((size_t)b * D3 + h * CHD) * NN;
    const uint16_t* ksr = qkv_sar + ((size_t)b * D3 + DIMC + h * CHD) * NN;

    if (w < 3) {
        const uint16_t* qb = (w == 0) ? qm : qsr;
        const uint16_t* kb = (w == 1) ? ksr : km;
        const int lm = lane & 15, g = lane >> 4;
        f32x4 acc[3][3];
#pragma unroll
        for (int i = 0; i < 3; ++i)
#pragma unroll
            for (int j = 0; j < 3; ++j) acc[i][j] = (f32x4){0.f, 0.f, 0.f, 0.f};
#pragma unroll 2
        for (int kk = 0; kk < CKW / 32; ++kk) {
            const int nb2 = n0 + kk * 32 + g * 8;
            FragU qf[3], kf[3];
#pragma unroll
            for (int i = 0; i < 3; ++i)
                qf[i].u4 = *(const uint4*)&qb[(size_t)(i * 16 + lm) * NN + nb2];
#pragma unroll
            for (int j = 0; j < 3; ++j)
                kf[j].u4 = *(const uint4*)&kb[(size_t)(j * 16 + lm) * NN + nb2];
#pragma unroll
            for (int i = 0; i < 3; ++i)
#pragma unroll
                for (int j = 0; j < 3; ++j)
                    acc[i][j] = __builtin_amdgcn_mfma_f32_16x16x32_bf16(
                        qf[i].s8, kf[j].s8, acc[i][j], 0, 0, 0);
        }
        float* pd = partial + (((size_t)pid * 3 + w) * NCK + ck) * 2304;
        const int g4 = g * 4;
#pragma unroll
        for (int i = 0; i < 3; ++i)
#pragma unroll
            for (int j = 0; j < 3; ++j)
#pragma unroll
                for (int r = 0; r < 4; ++r)
                    pd[(i * 16 + g4 + r) * 48 + j * 16 + lm] = acc[i][j][r];
    } else {
        // sumsq of 192 rows (0=q_ms 1=k_ms 2=q_sar 3=k_sar) over this chunk
#pragma unroll
        for (int rep = 0; rep < 3; ++rep) {
            const int rid = rep * 64 + lane;
            const int s = rid / CHD, c = rid % CHD;
            const uint16_t* rowp =
                (s == 0) ? qm  + (size_t)c * NN :
                (s == 1) ? km  + (size_t)c * NN :
                (s == 2) ? qsr + (size_t)c * NN :
                           ksr + (size_t)c * NN;
            float sum = 0.f;
#pragma unroll 4
            for (int u = 0; u < CKW / 8; ++u) {
                uint4 v = *(const uint4*)&rowp[n0 + u * 8];
                uint32_t uu[4] = {v.x, v.y, v.z, v.w};
#pragma unroll
                for (int q = 0; q < 4; ++q) {
                    float2 f = upk2(uu[q]);
                    sum = fmaf(f.x, f.x, fmaf(f.y, f.y, sum));
                }
            }
            sumsq[(((size_t)pid * NCK + ck) * 4 + s) * CHD + c] = sum;
        }
    }
}

// ---------- reduce chunks + norm scale + softmax ----------
__global__ __launch_bounds__(64) void k_softmax(
    const float* __restrict__ partial, const float* __restrict__ sumsq,
    const float* __restrict__ ms_temp, const float* __restrict__ sar_temp,
    float* __restrict__ A)
{
    const int lane = threadIdx.x;
    const int bi = blockIdx.x;
    const int c = bi % 48;
    const int pid = bi / 48;               // type*16 + b*4 + h
    const int h = pid & 3, b = (pid >> 2) & 3, type = pid >> 4;
    const int pid16 = b * 4 + h;
    float s;
    if (lane < 48) {
        float accv = 0.f;
        const float* pp = partial + ((size_t)pid16 * 3 + type) * NCK * 2304 + c * 48 + lane;
#pragma unroll 8
        for (int ck = 0; ck < NCK; ++ck) accv += pp[(size_t)ck * 2304];
        const int qset = (type == 0) ? 0 : 2;
        const int kset = (type == 1) ? 3 : 1;
        float qsum = 0.f, ksum = 0.f;
        const float* sq = sumsq + (size_t)pid16 * NCK * 4 * CHD;
#pragma unroll 8
        for (int ck = 0; ck < NCK; ++ck) {
            qsum += sq[ck * 4 * CHD + qset * CHD + c];
            ksum += sq[ck * 4 * CHD + kset * CHD + lane];
        }
        const float tval = (type == 1) ? sar_temp[h] : ms_temp[h];
        const float qsc = 1.0f / fmaxf(sqrtf(qsum), 1e-12f);
        const float ksc = 1.0f / fmaxf(sqrtf(ksum), 1e-12f);
        s = accv * qsc * ksc * tval;
    } else {
        s = -3.0e38f;
    }
    float m = s;
#pragma unroll
    for (int o = 32; o > 0; o >>= 1) m = fmaxf(m, __shfl_xor(m, o));
    float e = (lane < 48) ? __expf(s - m) : 0.f;
    float sum = e;
#pragma unroll
    for (int o = 32; o > 0; o >>= 1) sum += __shfl_xor(sum, o);
    if (lane < 48) A[(size_t)pid * 2304 + c * 48 + lane] = e / sum;
}

// ---------- MFMA apply: out[c][n] = sum_d A[c][d] V[d][n] ----------
__global__ __launch_bounds__(256) void k_apply_mfma(
    const float* __restrict__ A, const uint16_t* __restrict__ qkv_ms,
    const uint16_t* __restrict__ qkv_sar, uint16_t* __restrict__ attn)
{
    __shared__ uint16_t vs[256][40];
    __shared__ uint16_t as[48][40];
    __shared__ uint16_t sw_all[4][48][72];
    const int t = threadIdx.x;
    const int nb = blockIdx.x & 63;
    const int pid = blockIdx.x >> 6;
    const int h = pid & 3, b = (pid >> 2) & 3, type = pid >> 4;
    const int n0 = nb * 256;
    const uint16_t* vsrc = (type == 0) ? qkv_ms : qkv_sar;
    const uint16_t* vb = vsrc + ((size_t)b * D3 + 2 * DIMC + (size_t)h * CHD) * NN;
    const float* Ap = A + (size_t)pid * 2304;

    const int lane = t & 63, wvid = t >> 6;
    const int lm = lane & 15, g = lane >> 4;

    f32x4 acc[3][4];
#pragma unroll
    for (int i = 0; i < 3; ++i)
#pragma unroll
        for (int j = 0; j < 4; ++j) acc[i][j] = (f32x4){0.f, 0.f, 0.f, 0.f};

    for (int k0 = 0; k0 < 64; k0 += 32) {
        __syncthreads();
#pragma unroll
        for (int kh = 0; kh < 2; ++kh) {
            uint16_t vals[16];
#pragma unroll
            for (int j = 0; j < 16; ++j) {
                const int d = k0 + kh * 16 + j;
                vals[j] = (d < CHD) ? vb[(size_t)d * NN + n0 + t] : (uint16_t)0;
            }
            const int u0 = (2 * kh) ^ ((t >> 3) & 3);
            const int u1 = (2 * kh + 1) ^ ((t >> 3) & 3);
            *(uint4*)&vs[t][u0 * 8] = pack8(&vals[0]);
            *(uint4*)&vs[t][u1 * 8] = pack8(&vals[8]);
        }
        if (t < 192) {
            const int c = t >> 2, dq = t & 3;
            uint16_t av[8];
#pragma unroll
            for (int i = 0; i < 8; ++i) {
                const int d = k0 + dq * 8 + i;
                av[i] = (d < CHD) ? f2bf(Ap[c * CHD + d]) : (uint16_t)0;
            }
            const int u = dq ^ ((c >> 3) & 3);
            *(uint4*)&as[c][u * 8] = pack8(av);
        }
        __syncthreads();
        FragU afr[3], bfr[4];
#pragma unroll
        for (int mi = 0; mi < 3; ++mi) {
            const int row = mi * 16 + lm;
            afr[mi].u4 = *(const uint4*)&as[row][(g ^ ((row >> 3) & 3)) * 8];
        }
#pragma unroll
        for (int nj = 0; nj < 4; ++nj) {
            const int row = wvid * 64 + nj * 16 + lm;
            bfr[nj].u4 = *(const uint4*)&vs[row][(g ^ ((row >> 3) & 3)) * 8];
        }
#pragma unroll
        for (int mi = 0; mi < 3; ++mi)
#pragma unroll
            for (int nj = 0; nj < 4; ++nj)
                acc[mi][nj] = __builtin_amdgcn_mfma_f32_16x16x32_bf16(
                    afr[mi].s8, bfr[nj].s8, acc[mi][nj], 0, 0, 0);
    }

    uint16_t* ob = attn + (size_t)type * BB * DIMC * NN +
                   ((size_t)b * DIMC + (size_t)h * CHD) * NN;
    uint16_t* sw = &sw_all[wvid][0][0];
#pragma unroll
    for (int mi = 0; mi < 3; ++mi)
#pragma unroll
        for (int nj = 0; nj < 4; ++nj)
#pragma unroll
            for (int r = 0; r < 4; ++r)
                sw[(mi * 16 + g * 4 + r) * 72 + nj * 16 + lm] = f2bf(acc[mi][nj][r]);
    const int l8 = lane & 7, r8 = lane >> 3;
#pragma unroll
    for (int pass = 0; pass < 6; ++pass) {
        const int rr = pass * 8 + r8;
        uint4 v = *(const uint4*)&sw[rr * 72 + l8 * 8];
        *(uint4*)&ob[(size_t)rr * NN + n0 + wvid * 64 + l8 * 8] = v;
    }
}

extern "C" void kernel_launch(void* const* d_in, const int* in_sizes, int n_in,
                              void* d_out, int out_size, void* d_ws, size_t ws_size,
                              hipStream_t stream)
{
    const float* sar        = (const float*)d_in[0];
    const float* ms         = (const float*)d_in[1];
    const float* ms_qkv_w   = (const float*)d_in[2];
    const float* ms_qkv_b   = (const float*)d_in[3];
    const float* ms_dw_w    = (const float*)d_in[4];
    const float* ms_dw_b    = (const float*)d_in[5];
    const float* ms_temp    = (const float*)d_in[6];
    const float* sar_qkv_w  = (const float*)d_in[7];
    const float* sar_qkv_b  = (const float*)d_in[8];
    const float* sar_dw_w   = (const float*)d_in[9];
    const float* sar_dw_b   = (const float*)d_in[10];
    const float* sar_temp   = (const float*)d_in[11];
    const float* ms_proj_w  = (const float*)d_in[12];
    const float* ms_proj_b  = (const float*)d_in[13];
    const float* sar_proj_w = (const float*)d_in[14];
    const float* sar_proj_b = (const float*)d_in[15];

    char* ws = (char*)d_ws;
    // ws layout (bytes):
    //   [0,          75497472)  tmp bf16 (ms conv1x1 out) -> score partials
    //                           -> finally attn outputs (written by apply)
    //     partial: 16pid x 3type x 64ck x 2304 f32 = 28.3 MB at +0
    //     sumsq:   16pid x 64ck x 4set x 48  f32 = 0.79 MB at +32MB
    //   [75497472,  150994944)  qkv_ms bf16
    //   [150994944, 226492416)  qkv_sar bf16
    //   [230043648, 230486016)  softmaxed A f32
    // sar conv1x1 temp lives in d_out (fully overwritten by proj at the end).
    uint16_t* tmp     = (uint16_t*)(ws);
    uint16_t* tmp2    = (uint16_t*)(d_out);       // 75.5 MB scratch inside 201 MB d_out
    uint16_t* qkv_ms  = (uint16_t*)(ws + 75497472ull);
    uint16_t* qkv_sar = (uint16_t*)(ws + 150994944ull);
    float* partial    = (float*)(ws);
    float* sumsq      = (float*)(ws + 33554432ull);
    float* Amat       = (float*)(ws + 230043648ull);
    uint16_t* attn    = tmp;

    float* out_sar = (float*)d_out;
    float* out_ms  = out_sar + (size_t)BB * DIMC * NN;

    dim3 b256(256);
    k_conv_both<<<dim3(1024), b256, 0, stream>>>(
        ms, sar, ms_qkv_w, sar_qkv_w, ms_qkv_b, sar_qkv_b, tmp, tmp2);
    k_dw_both<<<dim3(1, 8, 2 * BB * D3), b256, 0, stream>>>(
        tmp, tmp2, ms_dw_w, sar_dw_w, ms_dw_b, sar_dw_b, qkv_ms, qkv_sar);

    k_scores_mfma<<<dim3(16 * NCK), b256, 0, stream>>>(qkv_ms, qkv_sar, partial, sumsq);
    k_softmax<<<dim3(48 * 48), dim3(64), 0, stream>>>(partial, sumsq, ms_temp, sar_temp, Amat);
    k_apply_mfma<<<dim3(48 * 64), b256, 0, stream>>>(Amat, qkv_ms, qkv_sar, attn);

    uint16_t* ms_self  = attn;
    uint16_t* sar_self = attn + (size_t)BB * DIMC * NN;
    uint16_t* crossb   = attn + 2ull * BB * DIMC * NN;
    k_proj_both<<<dim3(1024), b256, 0, stream>>>(
        sar_self, ms_self, crossb, sar_proj_w, ms_proj_w,
        sar_proj_b, ms_proj_b, sar, ms, out_sar, out_ms);
}

// Round 8
// 307.916 us; speedup vs baseline: 1.1284x; 1.1284x over previous
//
#include <hip/hip_runtime.h>
#include <hip/hip_bf16.h>
#include <cstdint>

#define DIMC 192
#define BB 4
#define NN 16384
#define D3 576
#define CHD 48
#define WWID 128
#define HHGT 128
#define NCK 64          // score chunks
#define CKW 256         // cols per score chunk

typedef short short8 __attribute__((ext_vector_type(8)));
typedef float f32x4 __attribute__((ext_vector_type(4)));

union FragU { uint4 u4; short8 s8; };

// ---------- bf16 helpers ----------
__device__ __forceinline__ float bf2f(uint16_t v) {
    return __uint_as_float(((uint32_t)v) << 16);
}
__device__ __forceinline__ float2 upk2(uint32_t u) {
    float2 r;
    r.x = __uint_as_float(u << 16);
    r.y = __uint_as_float(u & 0xffff0000u);
    return r;
}
__device__ __forceinline__ uint16_t f2bf(float f) {
    uint32_t x = __float_as_uint(f);
    return (uint16_t)((x + 0x7fffu + ((x >> 16) & 1u)) >> 16);
}
__device__ __forceinline__ uint4 pack8(const uint16_t* v) {
    uint4 u;
    u.x = (uint32_t)v[0] | ((uint32_t)v[1] << 16);
    u.y = (uint32_t)v[2] | ((uint32_t)v[3] << 16);
    u.z = (uint32_t)v[4] | ((uint32_t)v[5] << 16);
    u.w = (uint32_t)v[6] | ((uint32_t)v[7] << 16);
    return u;
}

// ---------- K0: weights fp32 -> bf16 (+ folded proj_ms weights) ----------
// o2a = Wa+Wb (applies to ms_self), o2b = Wb (applies to cross)
__global__ __launch_bounds__(256) void k_prep(
    const float* __restrict__ w0, const float* __restrict__ w1,
    const float* __restrict__ w2, const float* __restrict__ w3,
    uint16_t* __restrict__ o0, uint16_t* __restrict__ o1,
    uint16_t* __restrict__ o2a, uint16_t* __restrict__ o2b,
    uint16_t* __restrict__ o3)
{
    int i = blockIdx.x * 256 + threadIdx.x;
    if (i < 110592) { o0[i] = f2bf(w0[i]); return; }
    i -= 110592;
    if (i < 110592) { o1[i] = f2bf(w1[i]); return; }
    i -= 110592;
    if (i < 36864) {
        const int o = i / DIMC, c = i % DIMC;
        o2a[i] = f2bf(w2[o * 384 + c] + w2[o * 384 + DIMC + c]);
        o2b[i] = f2bf(w2[o * 384 + DIMC + c]);
        return;
    }
    i -= 36864;
    if (i < 36864) o3[i] = f2bf(w3[i]);
}

// ---------- merged qkv conv1x1 MFMA (ms + sar), W double-buffered ----------
// grid 1024: path = bid>>9. One barrier per m-block; W(mb+1) loads issued
// before MFMAs, LDS-written after (waits only on those loads, no stores in
// flight) -> fetch latency hidden under compute.
__global__ __launch_bounds__(256, 2) void k_conv_both(
    const float* __restrict__ ms, const float* __restrict__ sarp,
    const uint16_t* __restrict__ w_ms, const uint16_t* __restrict__ w_sar,
    const float* __restrict__ b_ms, const float* __restrict__ b_sar,
    uint16_t* __restrict__ out_ms, uint16_t* __restrict__ out_sar)
{
    __shared__ uint16_t xs[128][200];   // X [n][k]; later: wstB + store scratch
    __shared__ uint16_t wstA[64][200];
    const int t = threadIdx.x;
    const int bid = blockIdx.x;
    const int path = bid >> 9;
    const int rem = bid & 511;
    const int nb = rem & 127, b = rem >> 7;
    const int n0 = nb * 128;

    const float* x        = path ? sarp  : ms;
    const uint16_t* wsrc  = path ? w_sar : w_ms;
    const float* bias     = path ? b_sar : b_ms;
    uint16_t* out         = path ? out_sar : out_ms;

    const int lane = t & 63, wvid = t >> 6;
    const int lm = lane & 15, g = lane >> 4;
    const int wm = wvid >> 1, wn = wvid & 1;
    const int wm_ = t >> 2, wq = t & 3;

    // ---- stage X once: fp32 -> bf16, transposed to [n][k] ----
    {
        const int sn = t & 127, kh = t >> 7;
        const float* xcol = x + ((size_t)b * DIMC + kh * 96) * NN + n0 + sn;
        for (int u = 0; u < 12; ++u) {
            uint16_t vals[8];
#pragma unroll
            for (int j = 0; j < 8; ++j)
                vals[j] = f2bf(xcol[(size_t)(u * 8 + j) * NN]);
            *(uint4*)&xs[sn][(kh * 12 + u) * 8] = pack8(vals);
        }
    }
    // ---- stage W m-block 0 -> wstA ----
    {
        const uint16_t* wrow = wsrc + (size_t)wm_ * DIMC;
#pragma unroll
        for (int i = 0; i < 6; ++i) {
            const int unit = i * 4 + wq;
            *(uint4*)&wstA[wm_][unit * 8] = *(const uint4*)&wrow[unit * 8];
        }
    }
    __syncthreads();

    // ---- hoist B fragments (reused across all 9 m-blocks) ----
    FragU bfr[6][4];
#pragma unroll
    for (int ks = 0; ks < 6; ++ks)
#pragma unroll
        for (int nj = 0; nj < 4; ++nj) {
            const int row = wn * 64 + nj * 16 + lm;
            bfr[ks][nj].u4 = *(const uint4*)&xs[row][ks * 32 + g * 8];
        }
    __syncthreads();   // xs dead -> carve wstB + store scratch from it

    uint16_t* xsf  = &xs[0][0];
    uint16_t* wstB = xsf;                         // 64*200 = 12800 u16
    uint16_t* sw   = xsf + 12800 + wvid * 2304;   // wave-private 32x72

    for (int mb = 0; mb < 9; ++mb) {
        const uint16_t* cur = (mb & 1) ? wstB : &wstA[0][0];
        uint16_t* nxt       = (mb & 1) ? &wstA[0][0] : wstB;
        // (1) issue next W loads (no wait)
        uint4 wreg[6];
        if (mb < 8) {
            const uint16_t* wrow = wsrc + (size_t)((mb + 1) * 64 + wm_) * DIMC;
#pragma unroll
            for (int i = 0; i < 6; ++i)
                wreg[i] = *(const uint4*)&wrow[(i * 4 + wq) * 8];
        }
        // (2) MFMAs from cur (loads in flight)
        f32x4 acc[2][4];
#pragma unroll
        for (int mi = 0; mi < 2; ++mi)
#pragma unroll
            for (int nj = 0; nj < 4; ++nj) acc[mi][nj] = (f32x4){0.f, 0.f, 0.f, 0.f};
#pragma unroll
        for (int ks = 0; ks < 6; ++ks) {
            FragU afr[2];
#pragma unroll
            for (int mi = 0; mi < 2; ++mi) {
                const int row = wm * 32 + mi * 16 + lm;
                afr[mi].u4 = *(const uint4*)&cur[row * 200 + ks * 32 + g * 8];
            }
#pragma unroll
            for (int mi = 0; mi < 2; ++mi)
#pragma unroll
                for (int nj = 0; nj < 4; ++nj)
                    acc[mi][nj] = __builtin_amdgcn_mfma_f32_16x16x32_bf16(
                        afr[mi].s8, bfr[ks][nj].s8, acc[mi][nj], 0, 0, 0);
        }
        // (3) LDS-write next W (waits only on wreg loads; no stores in flight)
        if (mb < 8) {
#pragma unroll
            for (int i = 0; i < 6; ++i)
                *(uint4*)&nxt[wm_ * 200 + (i * 4 + wq) * 8] = wreg[i];
        }
        // (4) epilogue: acc -> wave-private LDS -> coalesced 16B stores
#pragma unroll
        for (int mi = 0; mi < 2; ++mi) {
            const int rbase = mb * 64 + wm * 32 + mi * 16 + g * 4;
            const float4 bv = *(const float4*)&bias[rbase];
            const float bva[4] = {bv.x, bv.y, bv.z, bv.w};
#pragma unroll
            for (int nj = 0; nj < 4; ++nj)
#pragma unroll
                for (int r = 0; r < 4; ++r)
                    sw[(mi * 16 + g * 4 + r) * 72 + nj * 16 + lm] =
                        f2bf(acc[mi][nj][r] + bva[r]);
        }
        const int l8 = lane & 7, r8 = lane >> 3;
#pragma unroll
        for (int pass = 0; pass < 4; ++pass) {
            const int rr = pass * 8 + r8;
            uint4 v = *(const uint4*)&sw[rr * 72 + l8 * 8];
            const int grow = mb * 64 + wm * 32 + rr;
            *(uint4*)&out[((size_t)b * D3 + grow) * NN + n0 + wn * 64 + l8 * 8] = v;
        }
        __syncthreads();   // one barrier per m-block
    }
}

// ---------- merged proj MFMA (sar 1 phase; ms 2 phases, prepped folded W) ----------
// W double-buffered like conv; X staged with full-width uint32 loads.
__global__ __launch_bounds__(256, 2) void k_proj_both(
    const uint16_t* __restrict__ sar_self, const uint16_t* __restrict__ ms_self,
    const uint16_t* __restrict__ crossb,
    const uint16_t* __restrict__ wp_sar, const uint16_t* __restrict__ wp1_ms,
    const uint16_t* __restrict__ wp2_ms,
    const float* __restrict__ b_sar, const float* __restrict__ b_ms,
    const float* __restrict__ resid_sar, const float* __restrict__ resid_ms,
    float* __restrict__ out_sar, float* __restrict__ out_ms)
{
    __shared__ uint16_t xs[128][200];
    __shared__ uint16_t wstA[64][200];
    const int t = threadIdx.x;
    const int bid = blockIdx.x;
    const int path = bid >> 9;          // 0=sar 1=ms
    const int rem = bid & 511;
    const int nb = rem & 127, b = rem >> 7;
    const int n0 = nb * 128;
    const int nph = path ? 2 : 1;

    const float* bias  = path ? b_ms : b_sar;
    const float* resid = path ? resid_ms : resid_sar;
    float* out         = path ? out_ms : out_sar;

    const int lane = t & 63, wvid = t >> 6;
    const int lm = lane & 15, g = lane >> 4;
    const int wm = wvid >> 1, wn = wvid & 1;
    const int wm_ = t >> 2, wq = t & 3;

    uint16_t* xsf  = &xs[0][0];
    uint16_t* wstB = xsf;               // carved from xs (dead after hoist)

    f32x4 acc[3][2][4];
#pragma unroll
    for (int mb = 0; mb < 3; ++mb)
#pragma unroll
        for (int mi = 0; mi < 2; ++mi)
#pragma unroll
            for (int nj = 0; nj < 4; ++nj) acc[mb][mi][nj] = (f32x4){0.f, 0.f, 0.f, 0.f};

    for (int ph = 0; ph < nph; ++ph) {
        const uint16_t* xsrc = path ? (ph ? crossb : ms_self) : sar_self;
        const uint16_t* wsrc = path ? (ph ? wp2_ms : wp1_ms) : wp_sar;
        // ---- stage X: uint32 loads (2 bf16 along n), transpose to [n][k] ----
        {
            const int p = t & 63, kg = t >> 6;
            const uint16_t* xcol = xsrc + ((size_t)b * DIMC + kg * 48) * NN + n0 + p * 2;
            for (int chn = 0; chn < 6; ++chn) {
                uint32_t v[8];
#pragma unroll
                for (int j = 0; j < 8; ++j)
                    v[j] = *(const uint32_t*)&xcol[(size_t)(chn * 8 + j) * NN];
                uint4 lo4, hi4;
                lo4.x = (v[0] & 0xffffu) | (v[1] << 16);
                lo4.y = (v[2] & 0xffffu) | (v[3] << 16);
                lo4.z = (v[4] & 0xffffu) | (v[5] << 16);
                lo4.w = (v[6] & 0xffffu) | (v[7] << 16);
                hi4.x = (v[0] >> 16) | (v[1] & 0xffff0000u);
                hi4.y = (v[2] >> 16) | (v[3] & 0xffff0000u);
                hi4.z = (v[4] >> 16) | (v[5] & 0xffff0000u);
                hi4.w = (v[6] >> 16) | (v[7] & 0xffff0000u);
                *(uint4*)&xs[p * 2][(kg * 6 + chn) * 8]     = lo4;
                *(uint4*)&xs[p * 2 + 1][(kg * 6 + chn) * 8] = hi4;
            }
        }
        // ---- stage W m-block 0 -> wstA ----
        {
            const uint16_t* wrow = wsrc + (size_t)wm_ * DIMC;
#pragma unroll
            for (int i = 0; i < 6; ++i) {
                const int unit = i * 4 + wq;
                *(uint4*)&wstA[wm_][unit * 8] = *(const uint4*)&wrow[unit * 8];
            }
        }
        __syncthreads();
        // ---- hoist B fragments ----
        FragU bfr[6][4];
#pragma unroll
        for (int ks = 0; ks < 6; ++ks)
#pragma unroll
            for (int nj = 0; nj < 4; ++nj) {
                const int row = wn * 64 + nj * 16 + lm;
                bfr[ks][nj].u4 = *(const uint4*)&xs[row][ks * 32 + g * 8];
            }
        __syncthreads();   // xs dead -> wstB usable

        for (int mb = 0; mb < 3; ++mb) {
            const uint16_t* cur = (mb & 1) ? wstB : &wstA[0][0];
            uint16_t* nxt       = (mb & 1) ? &wstA[0][0] : wstB;
            uint4 wreg[6];
            if (mb < 2) {
                const uint16_t* wrow = wsrc + (size_t)((mb + 1) * 64 + wm_) * DIMC;
#pragma unroll
                for (int i = 0; i < 6; ++i)
                    wreg[i] = *(const uint4*)&wrow[(i * 4 + wq) * 8];
            }
#pragma unroll
            for (int ks = 0; ks < 6; ++ks) {
                FragU afr[2];
#pragma unroll
                for (int mi = 0; mi < 2; ++mi) {
                    const int row = wm * 32 + mi * 16 + lm;
                    afr[mi].u4 = *(const uint4*)&cur[row * 200 + ks * 32 + g * 8];
                }
#pragma unroll
                for (int mi = 0; mi < 2; ++mi)
#pragma unroll
                    for (int nj = 0; nj < 4; ++nj)
                        acc[mb][mi][nj] = __builtin_amdgcn_mfma_f32_16x16x32_bf16(
                            afr[mi].s8, bfr[ks][nj].s8, acc[mb][mi][nj], 0, 0, 0);
            }
            if (mb < 2) {
#pragma unroll
                for (int i = 0; i < 6; ++i)
                    *(uint4*)&nxt[wm_ * 200 + (i * 4 + wq) * 8] = wreg[i];
            }
            __syncthreads();
        }
    }
    // ---- epilogue: bias + residual, fp32 out ----
#pragma unroll
    for (int mb = 0; mb < 3; ++mb)
#pragma unroll
        for (int mi = 0; mi < 2; ++mi) {
            const int rbase = mb * 64 + wm * 32 + mi * 16 + g * 4;
            const float4 bv = *(const float4*)&bias[rbase];
            const float bva[4] = {bv.x, bv.y, bv.z, bv.w};
#pragma unroll
            for (int nj = 0; nj < 4; ++nj) {
                const int gcol = n0 + wn * 64 + nj * 16 + lm;
#pragma unroll
                for (int r = 0; r < 4; ++r) {
                    const size_t idx = ((size_t)b * DIMC + rbase + r) * NN + gcol;
                    out[idx] = resid[idx] + acc[mb][mi][nj][r] + bva[r];
                }
            }
        }
}

// ---------- merged depthwise 3x3 + bias (ms + sar), 8 px/thread ----------
__global__ __launch_bounds__(256) void k_dw_both(
    const uint16_t* __restrict__ in0, const uint16_t* __restrict__ in1,
    const float* __restrict__ w_ms, const float* __restrict__ w_sar,
    const float* __restrict__ b_ms, const float* __restrict__ b_sar,
    uint16_t* __restrict__ out0, uint16_t* __restrict__ out1)
{
    const int t = threadIdx.x;
    int bc = blockIdx.z;
    const int path = (bc >= BB * D3);
    if (path) bc -= BB * D3;
    const int ch = bc % D3;
    const uint16_t* in = path ? in1 : in0;
    const float* w9    = path ? w_sar : w_ms;
    const float* bias  = path ? b_sar : b_ms;
    uint16_t* out      = path ? out1 : out0;

    const int xg = t & 15, yl = t >> 4;
    const int x0 = xg * 8;
    const int y = blockIdx.y * 16 + yl;
    const uint16_t* p = in + (size_t)bc * NN;
    float wv[9];
#pragma unroll
    for (int k = 0; k < 9; ++k) wv[k] = w9[ch * 9 + k];
    float r[3][10];
#pragma unroll
    for (int dy = 0; dy < 3; ++dy) {
        const int yy = y + dy - 1;
        if (yy < 0 || yy >= HHGT) {
#pragma unroll
            for (int j = 0; j < 10; ++j) r[dy][j] = 0.f;
        } else {
            const uint16_t* row = p + yy * WWID;
            uint4 u = *(const uint4*)(row + x0);
            const uint16_t* pv = (const uint16_t*)&u;
#pragma unroll
            for (int j = 0; j < 8; ++j) r[dy][j + 1] = bf2f(pv[j]);
            r[dy][0] = (x0 > 0) ? bf2f(row[x0 - 1]) : 0.f;
            r[dy][9] = (x0 + 8 < WWID) ? bf2f(row[x0 + 8]) : 0.f;
        }
    }
    const float base = bias[ch];
    uint16_t ov[8];
#pragma unroll
    for (int j = 0; j < 8; ++j) {
        float a = base;
#pragma unroll
        for (int dy = 0; dy < 3; ++dy)
#pragma unroll
            for (int dx = 0; dx < 3; ++dx)
                a = fmaf(r[dy][j + dx], wv[dy * 3 + dx], a);
        ov[j] = f2bf(a);
    }
    *(uint4*)(out + (size_t)bc * NN + y * WWID + x0) = pack8(ov);
}

// ---------- MFMA scores + fused norm partials (NCK chunks) ----------
__global__ __launch_bounds__(256) void k_scores_mfma(
    const uint16_t* __restrict__ qkv_ms, const uint16_t* __restrict__ qkv_sar,
    float* __restrict__ partial, float* __restrict__ sumsq)
{
    const int t = threadIdx.x;
    const int bid = blockIdx.x;
    const int ck = bid & (NCK - 1);
    const int pid = bid / NCK;         // b*4 + h
    const int h = pid & 3, b = pid >> 2;
    const int n0 = ck * CKW;
    const int lane = t & 63, w = t >> 6;

    const uint16_t* qm  = qkv_ms  + ((size_t)b * D3 + h * CHD) * NN;
    const uint16_t* km  = qkv_ms  + ((size_t)b * D3 + DIMC + h * CHD) * NN;
    const uint16_t* qsr = qkv_sar + ((size_t)b * D3 + h * CHD) * NN;
    const uint16_t* ksr = qkv_sar + ((size_t)b * D3 + DIMC + h * CHD) * NN;

    if (w < 3) {
        const uint16_t* qb = (w == 0) ? qm : qsr;
        const uint16_t* kb = (w == 1) ? ksr : km;
        const int lm = lane & 15, g = lane >> 4;
        f32x4 acc[3][3];
#pragma unroll
        for (int i = 0; i < 3; ++i)
#pragma unroll
            for (int j = 0; j < 3; ++j) acc[i][j] = (f32x4){0.f, 0.f, 0.f, 0.f};
#pragma unroll 2
        for (int kk = 0; kk < CKW / 32; ++kk) {
            const int nb2 = n0 + kk * 32 + g * 8;
            FragU qf[3], kf[3];
#pragma unroll
            for (int i = 0; i < 3; ++i)
                qf[i].u4 = *(const uint4*)&qb[(size_t)(i * 16 + lm) * NN + nb2];
#pragma unroll
            for (int j = 0; j < 3; ++j)
                kf[j].u4 = *(const uint4*)&kb[(size_t)(j * 16 + lm) * NN + nb2];
#pragma unroll
            for (int i = 0; i < 3; ++i)
#pragma unroll
                for (int j = 0; j < 3; ++j)
                    acc[i][j] = __builtin_amdgcn_mfma_f32_16x16x32_bf16(
                        qf[i].s8, kf[j].s8, acc[i][j], 0, 0, 0);
        }
        float* pd = partial + (((size_t)pid * 3 + w) * NCK + ck) * 2304;
        const int g4 = g * 4;
#pragma unroll
        for (int i = 0; i < 3; ++i)
#pragma unroll
            for (int j = 0; j < 3; ++j)
#pragma unroll
                for (int r = 0; r < 4; ++r)
                    pd[(i * 16 + g4 + r) * 48 + j * 16 + lm] = acc[i][j][r];
    } else {
        // sumsq of 192 rows (0=q_ms 1=k_ms 2=q_sar 3=k_sar) over this chunk
#pragma unroll
        for (int rep = 0; rep < 3; ++rep) {
            const int rid = rep * 64 + lane;
            const int s = rid / CHD, c = rid % CHD;
            const uint16_t* rowp =
                (s == 0) ? qm  + (size_t)c * NN :
                (s == 1) ? km  + (size_t)c * NN :
                (s == 2) ? qsr + (size_t)c * NN :
                           ksr + (size_t)c * NN;
            float sum = 0.f;
#pragma unroll 4
            for (int u = 0; u < CKW / 8; ++u) {
                uint4 v = *(const uint4*)&rowp[n0 + u * 8];
                uint32_t uu[4] = {v.x, v.y, v.z, v.w};
#pragma unroll
                for (int q = 0; q < 4; ++q) {
                    float2 f = upk2(uu[q]);
                    sum = fmaf(f.x, f.x, fmaf(f.y, f.y, sum));
                }
            }
            sumsq[(((size_t)pid * NCK + ck) * 4 + s) * CHD + c] = sum;
        }
    }
}

// ---------- reduce chunks + norm scale + softmax ----------
__global__ __launch_bounds__(64) void k_softmax(
    const float* __restrict__ partial, const float* __restrict__ sumsq,
    const float* __restrict__ ms_temp, const float* __restrict__ sar_temp,
    float* __restrict__ A)
{
    const int lane = threadIdx.x;
    const int bi = blockIdx.x;
    const int c = bi % 48;
    const int pid = bi / 48;               // type*16 + b*4 + h
    const int h = pid & 3, b = (pid >> 2) & 3, type = pid >> 4;
    const int pid16 = b * 4 + h;
    float s;
    if (lane < 48) {
        float accv = 0.f;
        const float* pp = partial + ((size_t)pid16 * 3 + type) * NCK * 2304 + c * 48 + lane;
#pragma unroll 8
        for (int ck = 0; ck < NCK; ++ck) accv += pp[(size_t)ck * 2304];
        const int qset = (type == 0) ? 0 : 2;
        const int kset = (type == 1) ? 3 : 1;
        float qsum = 0.f, ksum = 0.f;
        const float* sq = sumsq + (size_t)pid16 * NCK * 4 * CHD;
#pragma unroll 8
        for (int ck = 0; ck < NCK; ++ck) {
            qsum += sq[ck * 4 * CHD + qset * CHD + c];
            ksum += sq[ck * 4 * CHD + kset * CHD + lane];
        }
        const float tval = (type == 1) ? sar_temp[h] : ms_temp[h];
        const float qsc = 1.0f / fmaxf(sqrtf(qsum), 1e-12f);
        const float ksc = 1.0f / fmaxf(sqrtf(ksum), 1e-12f);
        s = accv * qsc * ksc * tval;
    } else {
        s = -3.0e38f;
    }
    float m = s;
#pragma unroll
    for (int o = 32; o > 0; o >>= 1) m = fmaxf(m, __shfl_xor(m, o));
    float e = (lane < 48) ? __expf(s - m) : 0.f;
    float sum = e;
#pragma unroll
    for (int o = 32; o > 0; o >>= 1) sum += __shfl_xor(sum, o);
    if (lane < 48) A[(size_t)pid * 2304 + c * 48 + lane] = e / sum;
}

// ---------- MFMA apply: out[c][n] = sum_d A[c][d] V[d][n] ----------
__global__ __launch_bounds__(256) void k_apply_mfma(
    const float* __restrict__ A, const uint16_t* __restrict__ qkv_ms,
    const uint16_t* __restrict__ qkv_sar, uint16_t* __restrict__ attn)
{
    __shared__ uint16_t vs[256][40];
    __shared__ uint16_t as[48][40];
    __shared__ uint16_t sw_all[4][48][72];
    const int t = threadIdx.x;
    const int nb = blockIdx.x & 63;
    const int pid = blockIdx.x >> 6;
    const int h = pid & 3, b = (pid >> 2) & 3, type = pid >> 4;
    const int n0 = nb * 256;
    const uint16_t* vsrc = (type == 0) ? qkv_ms : qkv_sar;
    const uint16_t* vb = vsrc + ((size_t)b * D3 + 2 * DIMC + (size_t)h * CHD) * NN;
    const float* Ap = A + (size_t)pid * 2304;

    const int lane = t & 63, wvid = t >> 6;
    const int lm = lane & 15, g = lane >> 4;

    f32x4 acc[3][4];
#pragma unroll
    for (int i = 0; i < 3; ++i)
#pragma unroll
        for (int j = 0; j < 4; ++j) acc[i][j] = (f32x4){0.f, 0.f, 0.f, 0.f};

    for (int k0 = 0; k0 < 64; k0 += 32) {
        __syncthreads();
#pragma unroll
        for (int kh = 0; kh < 2; ++kh) {
            uint16_t vals[16];
#pragma unroll
            for (int j = 0; j < 16; ++j) {
                const int d = k0 + kh * 16 + j;
                vals[j] = (d < CHD) ? vb[(size_t)d * NN + n0 + t] : (uint16_t)0;
            }
            const int u0 = (2 * kh) ^ ((t >> 3) & 3);
            const int u1 = (2 * kh + 1) ^ ((t >> 3) & 3);
            *(uint4*)&vs[t][u0 * 8] = pack8(&vals[0]);
            *(uint4*)&vs[t][u1 * 8] = pack8(&vals[8]);
        }
        if (t < 192) {
            const int c = t >> 2, dq = t & 3;
            uint16_t av[8];
#pragma unroll
            for (int i = 0; i < 8; ++i) {
                const int d = k0 + dq * 8 + i;
                av[i] = (d < CHD) ? f2bf(Ap[c * CHD + d]) : (uint16_t)0;
            }
            const int u = dq ^ ((c >> 3) & 3);
            *(uint4*)&as[c][u * 8] = pack8(av);
        }
        __syncthreads();
        FragU afr[3], bfr[4];
#pragma unroll
        for (int mi = 0; mi < 3; ++mi) {
            const int row = mi * 16 + lm;
            afr[mi].u4 = *(const uint4*)&as[row][(g ^ ((row >> 3) & 3)) * 8];
        }
#pragma unroll
        for (int nj = 0; nj < 4; ++nj) {
            const int row = wvid * 64 + nj * 16 + lm;
            bfr[nj].u4 = *(const uint4*)&vs[row][(g ^ ((row >> 3) & 3)) * 8];
        }
#pragma unroll
        for (int mi = 0; mi < 3; ++mi)
#pragma unroll
            for (int nj = 0; nj < 4; ++nj)
                acc[mi][nj] = __builtin_amdgcn_mfma_f32_16x16x32_bf16(
                    afr[mi].s8, bfr[nj].s8, acc[mi][nj], 0, 0, 0);
    }

    uint16_t* ob = attn + (size_t)type * BB * DIMC * NN +
                   ((size_t)b * DIMC + (size_t)h * CHD) * NN;
    uint16_t* sw = &sw_all[wvid][0][0];
#pragma unroll
    for (int mi = 0; mi < 3; ++mi)
#pragma unroll
        for (int nj = 0; nj < 4; ++nj)
#pragma unroll
            for (int r = 0; r < 4; ++r)
                sw[(mi * 16 + g * 4 + r) * 72 + nj * 16 + lm] = f2bf(acc[mi][nj][r]);
    const int l8 = lane & 7, r8 = lane >> 3;
#pragma unroll
    for (int pass = 0; pass < 6; ++pass) {
        const int rr = pass * 8 + r8;
        uint4 v = *(const uint4*)&sw[rr * 72 + l8 * 8];
        *(uint4*)&ob[(size_t)rr * NN + n0 + wvid * 64 + l8 * 8] = v;
    }
}

extern "C" void kernel_launch(void* const* d_in, const int* in_sizes, int n_in,
                              void* d_out, int out_size, void* d_ws, size_t ws_size,
                              hipStream_t stream)
{
    const float* sar        = (const float*)d_in[0];
    const float* ms         = (const float*)d_in[1];
    const float* ms_qkv_w   = (const float*)d_in[2];
    const float* ms_qkv_b   = (const float*)d_in[3];
    const float* ms_dw_w    = (const float*)d_in[4];
    const float* ms_dw_b    = (const float*)d_in[5];
    const float* ms_temp    = (const float*)d_in[6];
    const float* sar_qkv_w  = (const float*)d_in[7];
    const float* sar_qkv_b  = (const float*)d_in[8];
    const float* sar_dw_w   = (const float*)d_in[9];
    const float* sar_dw_b   = (const float*)d_in[10];
    const float* sar_temp   = (const float*)d_in[11];
    const float* ms_proj_w  = (const float*)d_in[12];
    const float* ms_proj_b  = (const float*)d_in[13];
    const float* sar_proj_w = (const float*)d_in[14];
    const float* sar_proj_b = (const float*)d_in[15];

    char* ws = (char*)d_ws;
    // ws layout (bytes):
    //   [0,          75497472)  tmp bf16 (ms conv1x1 out) -> score partials
    //                           -> finally attn outputs (written by apply)
    //     partial: 16pid x 3type x 64ck x 2304 f32 = 28.3 MB at +0
    //     sumsq:   16pid x 64ck x 4set x 48  f32 = 0.79 MB at +32MB
    //   [75497472,  150994944)  qkv_ms bf16
    //   [150994944, 226492416)  qkv_sar bf16
    //   [230043648, 230486016)  softmaxed A f32
    //   [230486016, 231149568)  bf16 weights (wq_ms, wq_sar, wp1_ms, wp2_ms, wp_sar)
    // sar conv1x1 temp lives in d_out (fully overwritten by proj at the end).
    uint16_t* tmp     = (uint16_t*)(ws);
    uint16_t* tmp2    = (uint16_t*)(d_out);
    uint16_t* qkv_ms  = (uint16_t*)(ws + 75497472ull);
    uint16_t* qkv_sar = (uint16_t*)(ws + 150994944ull);
    float* partial    = (float*)(ws);
    float* sumsq      = (float*)(ws + 33554432ull);
    float* Amat       = (float*)(ws + 230043648ull);
    uint16_t* wq_ms   = (uint16_t*)(ws + 230486016ull);
    uint16_t* wq_sar  = (uint16_t*)(ws + 230707200ull);
    uint16_t* wp1_ms  = (uint16_t*)(ws + 230928384ull);
    uint16_t* wp2_ms  = (uint16_t*)(ws + 231002112ull);
    uint16_t* wp_sar  = (uint16_t*)(ws + 231075840ull);
    uint16_t* attn    = tmp;

    float* out_sar = (float*)d_out;
    float* out_ms  = out_sar + (size_t)BB * DIMC * NN;

    dim3 b256(256);
    k_prep<<<dim3(1152), b256, 0, stream>>>(ms_qkv_w, sar_qkv_w, ms_proj_w, sar_proj_w,
                                            wq_ms, wq_sar, wp1_ms, wp2_ms, wp_sar);
    k_conv_both<<<dim3(1024), b256, 0, stream>>>(
        ms, sar, wq_ms, wq_sar, ms_qkv_b, sar_qkv_b, tmp, tmp2);
    k_dw_both<<<dim3(1, 8, 2 * BB * D3), b256, 0, stream>>>(
        tmp, tmp2, ms_dw_w, sar_dw_w, ms_dw_b, sar_dw_b, qkv_ms, qkv_sar);

    k_scores_mfma<<<dim3(16 * NCK), b256, 0, stream>>>(qkv_ms, qkv_sar, partial, sumsq);
    k_softmax<<<dim3(48 * 48), dim3(64), 0, stream>>>(partial, sumsq, ms_temp, sar_temp, Amat);
    k_apply_mfma<<<dim3(48 * 64), b256, 0, stream>>>(Amat, qkv_ms, qkv_sar, attn);

    uint16_t* ms_self  = attn;
    uint16_t* sar_self = attn + (size_t)BB * DIMC * NN;
    uint16_t* crossb   = attn + 2ull * BB * DIMC * NN;
    k_proj_both<<<dim3(1024), b256, 0, stream>>>(
        sar_self, ms_self, crossb, wp_sar, wp1_ms, wp2_ms,
        sar_proj_b, ms_proj_b, sar, ms, out_sar, out_ms);
}

// Round 9
// 281.323 us; speedup vs baseline: 1.2350x; 1.0945x over previous
//
#include <hip/hip_runtime.h>
#include <hip/hip_bf16.h>
#include <cstdint>

#define DIMC 192
#define BB 4
#define NN 16384
#define D3 576
#define CHD 48
#define WWID 128
#define HHGT 128
#define NCK 64          // score chunks
#define CKW 256         // cols per score chunk

typedef short short8 __attribute__((ext_vector_type(8)));
typedef float f32x4 __attribute__((ext_vector_type(4)));

union FragU { uint4 u4; short8 s8; };

// ---------- bf16 helpers ----------
__device__ __forceinline__ float bf2f(uint16_t v) {
    return __uint_as_float(((uint32_t)v) << 16);
}
__device__ __forceinline__ float2 upk2(uint32_t u) {
    float2 r;
    r.x = __uint_as_float(u << 16);
    r.y = __uint_as_float(u & 0xffff0000u);
    return r;
}
__device__ __forceinline__ uint16_t f2bf(float f) {
    uint32_t x = __float_as_uint(f);
    return (uint16_t)((x + 0x7fffu + ((x >> 16) & 1u)) >> 16);
}
__device__ __forceinline__ uint4 pack8(const uint16_t* v) {
    uint4 u;
    u.x = (uint32_t)v[0] | ((uint32_t)v[1] << 16);
    u.y = (uint32_t)v[2] | ((uint32_t)v[3] << 16);
    u.z = (uint32_t)v[4] | ((uint32_t)v[5] << 16);
    u.w = (uint32_t)v[6] | ((uint32_t)v[7] << 16);
    return u;
}

// ---------- K0: weights fp32 -> bf16 (+ folded proj_ms weights) ----------
// o2a = Wa+Wb (applies to ms_self), o2b = Wb (applies to cross)
__global__ __launch_bounds__(256) void k_prep(
    const float* __restrict__ w0, const float* __restrict__ w1,
    const float* __restrict__ w2, const float* __restrict__ w3,
    uint16_t* __restrict__ o0, uint16_t* __restrict__ o1,
    uint16_t* __restrict__ o2a, uint16_t* __restrict__ o2b,
    uint16_t* __restrict__ o3)
{
    int i = blockIdx.x * 256 + threadIdx.x;
    if (i < 110592) { o0[i] = f2bf(w0[i]); return; }
    i -= 110592;
    if (i < 110592) { o1[i] = f2bf(w1[i]); return; }
    i -= 110592;
    if (i < 36864) {
        const int o = i / DIMC, c = i % DIMC;
        o2a[i] = f2bf(w2[o * 384 + c] + w2[o * 384 + DIMC + c]);
        o2b[i] = f2bf(w2[o * 384 + DIMC + c]);
        return;
    }
    i -= 36864;
    if (i < 36864) o3[i] = f2bf(w3[i]);
}

// ---------- merged qkv conv1x1 MFMA (ms + sar), W double-buffered ----------
__global__ __launch_bounds__(256, 2) void k_conv_both(
    const float* __restrict__ ms, const float* __restrict__ sarp,
    const uint16_t* __restrict__ w_ms, const uint16_t* __restrict__ w_sar,
    const float* __restrict__ b_ms, const float* __restrict__ b_sar,
    uint16_t* __restrict__ out_ms, uint16_t* __restrict__ out_sar)
{
    __shared__ uint16_t xs[128][200];   // X [n][k]; later: wstB + store scratch
    __shared__ uint16_t wstA[64][200];
    const int t = threadIdx.x;
    const int bid = blockIdx.x;
    const int path = bid >> 9;
    const int rem = bid & 511;
    const int nb = rem & 127, b = rem >> 7;
    const int n0 = nb * 128;

    const float* x        = path ? sarp  : ms;
    const uint16_t* wsrc  = path ? w_sar : w_ms;
    const float* bias     = path ? b_sar : b_ms;
    uint16_t* out         = path ? out_sar : out_ms;

    const int lane = t & 63, wvid = t >> 6;
    const int lm = lane & 15, g = lane >> 4;
    const int wm = wvid >> 1, wn = wvid & 1;
    const int wm_ = t >> 2, wq = t & 3;

    // ---- stage X once: fp32 -> bf16, transposed to [n][k] ----
    {
        const int sn = t & 127, kh = t >> 7;
        const float* xcol = x + ((size_t)b * DIMC + kh * 96) * NN + n0 + sn;
        for (int u = 0; u < 12; ++u) {
            uint16_t vals[8];
#pragma unroll
            for (int j = 0; j < 8; ++j)
                vals[j] = f2bf(xcol[(size_t)(u * 8 + j) * NN]);
            *(uint4*)&xs[sn][(kh * 12 + u) * 8] = pack8(vals);
        }
    }
    // ---- stage W m-block 0 -> wstA ----
    {
        const uint16_t* wrow = wsrc + (size_t)wm_ * DIMC;
#pragma unroll
        for (int i = 0; i < 6; ++i) {
            const int unit = i * 4 + wq;
            *(uint4*)&wstA[wm_][unit * 8] = *(const uint4*)&wrow[unit * 8];
        }
    }
    __syncthreads();

    // ---- hoist B fragments (reused across all 9 m-blocks) ----
    FragU bfr[6][4];
#pragma unroll
    for (int ks = 0; ks < 6; ++ks)
#pragma unroll
        for (int nj = 0; nj < 4; ++nj) {
            const int row = wn * 64 + nj * 16 + lm;
            bfr[ks][nj].u4 = *(const uint4*)&xs[row][ks * 32 + g * 8];
        }
    __syncthreads();   // xs dead -> carve wstB + store scratch from it

    uint16_t* xsf  = &xs[0][0];
    uint16_t* wstB = xsf;                         // 64*200 = 12800 u16
    uint16_t* sw   = xsf + 12800 + wvid * 2304;   // wave-private 32x72

    for (int mb = 0; mb < 9; ++mb) {
        const uint16_t* cur = (mb & 1) ? wstB : &wstA[0][0];
        uint16_t* nxt       = (mb & 1) ? &wstA[0][0] : wstB;
        // (1) issue next W loads (no wait)
        uint4 wreg[6];
        if (mb < 8) {
            const uint16_t* wrow = wsrc + (size_t)((mb + 1) * 64 + wm_) * DIMC;
#pragma unroll
            for (int i = 0; i < 6; ++i)
                wreg[i] = *(const uint4*)&wrow[(i * 4 + wq) * 8];
        }
        // (2) MFMAs from cur (loads in flight)
        f32x4 acc[2][4];
#pragma unroll
        for (int mi = 0; mi < 2; ++mi)
#pragma unroll
            for (int nj = 0; nj < 4; ++nj) acc[mi][nj] = (f32x4){0.f, 0.f, 0.f, 0.f};
#pragma unroll
        for (int ks = 0; ks < 6; ++ks) {
            FragU afr[2];
#pragma unroll
            for (int mi = 0; mi < 2; ++mi) {
                const int row = wm * 32 + mi * 16 + lm;
                afr[mi].u4 = *(const uint4*)&cur[row * 200 + ks * 32 + g * 8];
            }
#pragma unroll
            for (int mi = 0; mi < 2; ++mi)
#pragma unroll
                for (int nj = 0; nj < 4; ++nj)
                    acc[mi][nj] = __builtin_amdgcn_mfma_f32_16x16x32_bf16(
                        afr[mi].s8, bfr[ks][nj].s8, acc[mi][nj], 0, 0, 0);
        }
        // (3) LDS-write next W (waits only on wreg loads; no stores in flight)
        if (mb < 8) {
#pragma unroll
            for (int i = 0; i < 6; ++i)
                *(uint4*)&nxt[wm_ * 200 + (i * 4 + wq) * 8] = wreg[i];
        }
        // (4) epilogue: acc -> wave-private LDS -> coalesced 16B stores
#pragma unroll
        for (int mi = 0; mi < 2; ++mi) {
            const int rbase = mb * 64 + wm * 32 + mi * 16 + g * 4;
            const float4 bv = *(const float4*)&bias[rbase];
            const float bva[4] = {bv.x, bv.y, bv.z, bv.w};
#pragma unroll
            for (int nj = 0; nj < 4; ++nj)
#pragma unroll
                for (int r = 0; r < 4; ++r)
                    sw[(mi * 16 + g * 4 + r) * 72 + nj * 16 + lm] =
                        f2bf(acc[mi][nj][r] + bva[r]);
        }
        const int l8 = lane & 7, r8 = lane >> 3;
#pragma unroll
        for (int pass = 0; pass < 4; ++pass) {
            const int rr = pass * 8 + r8;
            uint4 v = *(const uint4*)&sw[rr * 72 + l8 * 8];
            const int grow = mb * 64 + wm * 32 + rr;
            *(uint4*)&out[((size_t)b * D3 + grow) * NN + n0 + wn * 64 + l8 * 8] = v;
        }
        __syncthreads();   // one barrier per m-block
    }
}

// ---------- merged proj MFMA (sar 1 phase; ms 2 phases, prepped folded W) ----------
__global__ __launch_bounds__(256, 2) void k_proj_both(
    const uint16_t* __restrict__ sar_self, const uint16_t* __restrict__ ms_self,
    const uint16_t* __restrict__ crossb,
    const uint16_t* __restrict__ wp_sar, const uint16_t* __restrict__ wp1_ms,
    const uint16_t* __restrict__ wp2_ms,
    const float* __restrict__ b_sar, const float* __restrict__ b_ms,
    const float* __restrict__ resid_sar, const float* __restrict__ resid_ms,
    float* __restrict__ out_sar, float* __restrict__ out_ms)
{
    __shared__ uint16_t xs[128][200];
    __shared__ uint16_t wstA[64][200];
    const int t = threadIdx.x;
    const int bid = blockIdx.x;
    const int path = bid >> 9;          // 0=sar 1=ms
    const int rem = bid & 511;
    const int nb = rem & 127, b = rem >> 7;
    const int n0 = nb * 128;
    const int nph = path ? 2 : 1;

    const float* bias  = path ? b_ms : b_sar;
    const float* resid = path ? resid_ms : resid_sar;
    float* out         = path ? out_ms : out_sar;

    const int lane = t & 63, wvid = t >> 6;
    const int lm = lane & 15, g = lane >> 4;
    const int wm = wvid >> 1, wn = wvid & 1;
    const int wm_ = t >> 2, wq = t & 3;

    uint16_t* xsf  = &xs[0][0];
    uint16_t* wstB = xsf;               // carved from xs (dead after hoist)

    f32x4 acc[3][2][4];
#pragma unroll
    for (int mb = 0; mb < 3; ++mb)
#pragma unroll
        for (int mi = 0; mi < 2; ++mi)
#pragma unroll
            for (int nj = 0; nj < 4; ++nj) acc[mb][mi][nj] = (f32x4){0.f, 0.f, 0.f, 0.f};

    for (int ph = 0; ph < nph; ++ph) {
        const uint16_t* xsrc = path ? (ph ? crossb : ms_self) : sar_self;
        const uint16_t* wsrc = path ? (ph ? wp2_ms : wp1_ms) : wp_sar;
        // ---- stage X: uint32 loads (2 bf16 along n), transpose to [n][k] ----
        {
            const int p = t & 63, kg = t >> 6;
            const uint16_t* xcol = xsrc + ((size_t)b * DIMC + kg * 48) * NN + n0 + p * 2;
            for (int chn = 0; chn < 6; ++chn) {
                uint32_t v[8];
#pragma unroll
                for (int j = 0; j < 8; ++j)
                    v[j] = *(const uint32_t*)&xcol[(size_t)(chn * 8 + j) * NN];
                uint4 lo4, hi4;
                lo4.x = (v[0] & 0xffffu) | (v[1] << 16);
                lo4.y = (v[2] & 0xffffu) | (v[3] << 16);
                lo4.z = (v[4] & 0xffffu) | (v[5] << 16);
                lo4.w = (v[6] & 0xffffu) | (v[7] << 16);
                hi4.x = (v[0] >> 16) | (v[1] & 0xffff0000u);
                hi4.y = (v[2] >> 16) | (v[3] & 0xffff0000u);
                hi4.z = (v[4] >> 16) | (v[5] & 0xffff0000u);
                hi4.w = (v[6] >> 16) | (v[7] & 0xffff0000u);
                *(uint4*)&xs[p * 2][(kg * 6 + chn) * 8]     = lo4;
                *(uint4*)&xs[p * 2 + 1][(kg * 6 + chn) * 8] = hi4;
            }
        }
        // ---- stage W m-block 0 -> wstA ----
        {
            const uint16_t* wrow = wsrc + (size_t)wm_ * DIMC;
#pragma unroll
            for (int i = 0; i < 6; ++i) {
                const int unit = i * 4 + wq;
                *(uint4*)&wstA[wm_][unit * 8] = *(const uint4*)&wrow[unit * 8];
            }
        }
        __syncthreads();
        // ---- hoist B fragments ----
        FragU bfr[6][4];
#pragma unroll
        for (int ks = 0; ks < 6; ++ks)
#pragma unroll
            for (int nj = 0; nj < 4; ++nj) {
                const int row = wn * 64 + nj * 16 + lm;
                bfr[ks][nj].u4 = *(const uint4*)&xs[row][ks * 32 + g * 8];
            }
        __syncthreads();   // xs dead -> wstB usable

        for (int mb = 0; mb < 3; ++mb) {
            const uint16_t* cur = (mb & 1) ? wstB : &wstA[0][0];
            uint16_t* nxt       = (mb & 1) ? &wstA[0][0] : wstB;
            uint4 wreg[6];
            if (mb < 2) {
                const uint16_t* wrow = wsrc + (size_t)((mb + 1) * 64 + wm_) * DIMC;
#pragma unroll
                for (int i = 0; i < 6; ++i)
                    wreg[i] = *(const uint4*)&wrow[(i * 4 + wq) * 8];
            }
#pragma unroll
            for (int ks = 0; ks < 6; ++ks) {
                FragU afr[2];
#pragma unroll
                for (int mi = 0; mi < 2; ++mi) {
                    const int row = wm * 32 + mi * 16 + lm;
                    afr[mi].u4 = *(const uint4*)&cur[row * 200 + ks * 32 + g * 8];
                }
#pragma unroll
                for (int mi = 0; mi < 2; ++mi)
#pragma unroll
                    for (int nj = 0; nj < 4; ++nj)
                        acc[mb][mi][nj] = __builtin_amdgcn_mfma_f32_16x16x32_bf16(
                            afr[mi].s8, bfr[ks][nj].s8, acc[mb][mi][nj], 0, 0, 0);
            }
            if (mb < 2) {
#pragma unroll
                for (int i = 0; i < 6; ++i)
                    *(uint4*)&nxt[wm_ * 200 + (i * 4 + wq) * 8] = wreg[i];
            }
            __syncthreads();
        }
    }
    // ---- epilogue: bias + residual, fp32 out ----
#pragma unroll
    for (int mb = 0; mb < 3; ++mb)
#pragma unroll
        for (int mi = 0; mi < 2; ++mi) {
            const int rbase = mb * 64 + wm * 32 + mi * 16 + g * 4;
            const float4 bv = *(const float4*)&bias[rbase];
            const float bva[4] = {bv.x, bv.y, bv.z, bv.w};
#pragma unroll
            for (int nj = 0; nj < 4; ++nj) {
                const int gcol = n0 + wn * 64 + nj * 16 + lm;
#pragma unroll
                for (int r = 0; r < 4; ++r) {
                    const size_t idx = ((size_t)b * DIMC + rbase + r) * NN + gcol;
                    out[idx] = resid[idx] + acc[mb][mi][nj][r] + bva[r];
                }
            }
        }
}

// ---------- merged depthwise 3x3 + bias, LDS-staged 32-row tiles ----------
// grid: bid = (channel-instance << 2) | y-block. Each block: one (path,b,ch),
// 32 output rows. Stage 34 rows x 128 px (halo, zero-padded) coalesced into
// LDS; each thread computes 16 contiguous px of one row from LDS.
__global__ __launch_bounds__(256) void k_dw_both(
    const uint16_t* __restrict__ in0, const uint16_t* __restrict__ in1,
    const float* __restrict__ w_ms, const float* __restrict__ w_sar,
    const float* __restrict__ b_ms, const float* __restrict__ b_sar,
    uint16_t* __restrict__ out0, uint16_t* __restrict__ out1)
{
    __shared__ uint16_t lds[34 * 136];   // 136 stride: +4 banks/row, 16B aligned
    const int t = threadIdx.x;
    const int bid = blockIdx.x;
    const int yb = bid & 3;
    int bc = bid >> 2;
    const int path = (bc >= BB * D3);
    if (path) bc -= BB * D3;
    const int ch = bc % D3;
    const uint16_t* in = path ? in1 : in0;
    const float* w9    = path ? w_sar : w_ms;
    const float* bias  = path ? b_sar : b_ms;
    uint16_t* out      = path ? out1 : out0;

    const int y0 = yb * 32;
    const uint16_t* p = in + (size_t)bc * NN;

    // ---- stage 34 rows (y0-1 .. y0+32), zero-pad outside image ----
#pragma unroll
    for (int it = 0; it < 3; ++it) {
        const int u = it * 256 + t;
        if (u < 34 * 16) {
            const int r = u >> 4, seg = u & 15;
            const int gy = y0 - 1 + r;
            uint4 v = (gy >= 0 && gy < HHGT)
                ? *(const uint4*)(p + gy * WWID + seg * 8)
                : (uint4){0u, 0u, 0u, 0u};
            *(uint4*)&lds[r * 136 + seg * 8] = v;
        }
    }
    float wv[9];
#pragma unroll
    for (int k = 0; k < 9; ++k) wv[k] = w9[ch * 9 + k];
    const float base = bias[ch];
    __syncthreads();

    // ---- compute: thread -> (row lr, 16-px segment) ----
    const int lr = t >> 3;            // 0..31
    const int x0 = (t & 7) * 16;
    float rv[3][18];
#pragma unroll
    for (int dy = 0; dy < 3; ++dy) {
        const uint16_t* lp = &lds[(lr + dy) * 136 + x0];
        uint4 a = *(const uint4*)lp;
        uint4 bq = *(const uint4*)(lp + 8);
        const uint16_t* av = (const uint16_t*)&a;
        const uint16_t* bv2 = (const uint16_t*)&bq;
#pragma unroll
        for (int j = 0; j < 8; ++j) {
            rv[dy][1 + j] = bf2f(av[j]);
            rv[dy][9 + j] = bf2f(bv2[j]);
        }
        rv[dy][0]  = (x0 > 0) ? bf2f(lds[(lr + dy) * 136 + x0 - 1]) : 0.f;
        rv[dy][17] = (x0 + 16 < WWID) ? bf2f(lds[(lr + dy) * 136 + x0 + 16]) : 0.f;
    }
    uint16_t ov[16];
#pragma unroll
    for (int j = 0; j < 16; ++j) {
        float a = base;
#pragma unroll
        for (int dy = 0; dy < 3; ++dy)
            a = fmaf(rv[dy][j], wv[dy * 3],
                fmaf(rv[dy][j + 1], wv[dy * 3 + 1],
                fmaf(rv[dy][j + 2], wv[dy * 3 + 2], a)));
        ov[j] = f2bf(a);
    }
    uint16_t* ob = out + (size_t)bc * NN + (y0 + lr) * WWID + x0;
    *(uint4*)ob       = pack8(&ov[0]);
    *(uint4*)(ob + 8) = pack8(&ov[8]);
}

// ---------- MFMA scores + fused norm partials (NCK chunks) ----------
__global__ __launch_bounds__(256) void k_scores_mfma(
    const uint16_t* __restrict__ qkv_ms, const uint16_t* __restrict__ qkv_sar,
    float* __restrict__ partial, float* __restrict__ sumsq)
{
    const int t = threadIdx.x;
    const int bid = blockIdx.x;
    const int ck = bid & (NCK - 1);
    const int pid = bid / NCK;         // b*4 + h
    const int h = pid & 3, b = pid >> 2;
    const int n0 = ck * CKW;
    const int lane = t & 63, w = t >> 6;

    const uint16_t* qm  = qkv_ms  + ((size_t)b * D3 + h * CHD) * NN;
    const uint16_t* km  = qkv_ms  + ((size_t)b * D3 + DIMC + h * CHD) * NN;
    const uint16_t* qsr = qkv_sar + ((size_t)b * D3 + h * CHD) * NN;
    const uint16_t* ksr = qkv_sar + ((size_t)b * D3 + DIMC + h * CHD) * NN;

    if (w < 3) {
        const uint16_t* qb = (w == 0) ? qm : qsr;
        const uint16_t* kb = (w == 1) ? ksr : km;
        const int lm = lane & 15, g = lane >> 4;
        f32x4 acc[3][3];
#pragma unroll
        for (int i = 0; i < 3; ++i)
#pragma unroll
            for (int j = 0; j < 3; ++j) acc[i][j] = (f32x4){0.f, 0.f, 0.f, 0.f};
#pragma unroll 2
        for (int kk = 0; kk < CKW / 32; ++kk) {
            const int nb2 = n0 + kk * 32 + g * 8;
            FragU qf[3], kf[3];
#pragma unroll
            for (int i = 0; i < 3; ++i)
                qf[i].u4 = *(const uint4*)&qb[(size_t)(i * 16 + lm) * NN + nb2];
#pragma unroll
            for (int j = 0; j < 3; ++j)
                kf[j].u4 = *(const uint4*)&kb[(size_t)(j * 16 + lm) * NN + nb2];
#pragma unroll
            for (int i = 0; i < 3; ++i)
#pragma unroll
                for (int j = 0; j < 3; ++j)
                    acc[i][j] = __builtin_amdgcn_mfma_f32_16x16x32_bf16(
                        qf[i].s8, kf[j].s8, acc[i][j], 0, 0, 0);
        }
        float* pd = partial + (((size_t)pid * 3 + w) * NCK + ck) * 2304;
        const int g4 = g * 4;
#pragma unroll
        for (int i = 0; i < 3; ++i)
#pragma unroll
            for (int j = 0; j < 3; ++j)
#pragma unroll
                for (int r = 0; r < 4; ++r)
                    pd[(i * 16 + g4 + r) * 48 + j * 16 + lm] = acc[i][j][r];
    } else {
        // sumsq of 192 rows (0=q_ms 1=k_ms 2=q_sar 3=k_sar) over this chunk
#pragma unroll
        for (int rep = 0; rep < 3; ++rep) {
            const int rid = rep * 64 + lane;
            const int s = rid / CHD, c = rid % CHD;
            const uint16_t* rowp =
                (s == 0) ? qm  + (size_t)c * NN :
                (s == 1) ? km  + (size_t)c * NN :
                (s == 2) ? qsr + (size_t)c * NN :
                           ksr + (size_t)c * NN;
            float sum = 0.f;
#pragma unroll 4
            for (int u = 0; u < CKW / 8; ++u) {
                uint4 v = *(const uint4*)&rowp[n0 + u * 8];
                uint32_t uu[4] = {v.x, v.y, v.z, v.w};
#pragma unroll
                for (int q = 0; q < 4; ++q) {
                    float2 f = upk2(uu[q]);
                    sum = fmaf(f.x, f.x, fmaf(f.y, f.y, sum));
                }
            }
            sumsq[(((size_t)pid * NCK + ck) * 4 + s) * CHD + c] = sum;
        }
    }
}

// ---------- reduce chunks + norm scale + softmax ----------
__global__ __launch_bounds__(64) void k_softmax(
    const float* __restrict__ partial, const float* __restrict__ sumsq,
    const float* __restrict__ ms_temp, const float* __restrict__ sar_temp,
    float* __restrict__ A)
{
    const int lane = threadIdx.x;
    const int bi = blockIdx.x;
    const int c = bi % 48;
    const int pid = bi / 48;               // type*16 + b*4 + h
    const int h = pid & 3, b = (pid >> 2) & 3, type = pid >> 4;
    const int pid16 = b * 4 + h;
    float s;
    if (lane < 48) {
        float accv = 0.f;
        const float* pp = partial + ((size_t)pid16 * 3 + type) * NCK * 2304 + c * 48 + lane;
#pragma unroll 8
        for (int ck = 0; ck < NCK; ++ck) accv += pp[(size_t)ck * 2304];
        const int qset = (type == 0) ? 0 : 2;
        const int kset = (type == 1) ? 3 : 1;
        float qsum = 0.f, ksum = 0.f;
        const float* sq = sumsq + (size_t)pid16 * NCK * 4 * CHD;
#pragma unroll 8
        for (int ck = 0; ck < NCK; ++ck) {
            qsum += sq[ck * 4 * CHD + qset * CHD + c];
            ksum += sq[ck * 4 * CHD + kset * CHD + lane];
        }
        const float tval = (type == 1) ? sar_temp[h] : ms_temp[h];
        const float qsc = 1.0f / fmaxf(sqrtf(qsum), 1e-12f);
        const float ksc = 1.0f / fmaxf(sqrtf(ksum), 1e-12f);
        s = accv * qsc * ksc * tval;
    } else {
        s = -3.0e38f;
    }
    float m = s;
#pragma unroll
    for (int o = 32; o > 0; o >>= 1) m = fmaxf(m, __shfl_xor(m, o));
    float e = (lane < 48) ? __expf(s - m) : 0.f;
    float sum = e;
#pragma unroll
    for (int o = 32; o > 0; o >>= 1) sum += __shfl_xor(sum, o);
    if (lane < 48) A[(size_t)pid * 2304 + c * 48 + lane] = e / sum;
}

// ---------- MFMA apply: out[c][n] = sum_d A[c][d] V[d][n] ----------
__global__ __launch_bounds__(256) void k_apply_mfma(
    const float* __restrict__ A, const uint16_t* __restrict__ qkv_ms,
    const uint16_t* __restrict__ qkv_sar, uint16_t* __restrict__ attn)
{
    __shared__ uint16_t vs[256][40];
    __shared__ uint16_t as[48][40];
    __shared__ uint16_t sw_all[4][48][72];
    const int t = threadIdx.x;
    const int nb = blockIdx.x & 63;
    const int pid = blockIdx.x >> 6;
    const int h = pid & 3, b = (pid >> 2) & 3, type = pid >> 4;
    const int n0 = nb * 256;
    const uint16_t* vsrc = (type == 0) ? qkv_ms : qkv_sar;
    const uint16_t* vb = vsrc + ((size_t)b * D3 + 2 * DIMC + (size_t)h * CHD) * NN;
    const float* Ap = A + (size_t)pid * 2304;

    const int lane = t & 63, wvid = t >> 6;
    const int lm = lane & 15, g = lane >> 4;

    f32x4 acc[3][4];
#pragma unroll
    for (int i = 0; i < 3; ++i)
#pragma unroll
        for (int j = 0; j < 4; ++j) acc[i][j] = (f32x4){0.f, 0.f, 0.f, 0.f};

    for (int k0 = 0; k0 < 64; k0 += 32) {
        __syncthreads();
#pragma unroll
        for (int kh = 0; kh < 2; ++kh) {
            uint16_t vals[16];
#pragma unroll
            for (int j = 0; j < 16; ++j) {
                const int d = k0 + kh * 16 + j;
                vals[j] = (d < CHD) ? vb[(size_t)d * NN + n0 + t] : (uint16_t)0;
            }
            const int u0 = (2 * kh) ^ ((t >> 3) & 3);
            const int u1 = (2 * kh + 1) ^ ((t >> 3) & 3);
            *(uint4*)&vs[t][u0 * 8] = pack8(&vals[0]);
            *(uint4*)&vs[t][u1 * 8] = pack8(&vals[8]);
        }
        if (t < 192) {
            const int c = t >> 2, dq = t & 3;
            uint16_t av[8];
#pragma unroll
            for (int i = 0; i < 8; ++i) {
                const int d = k0 + dq * 8 + i;
                av[i] = (d < CHD) ? f2bf(Ap[c * CHD + d]) : (uint16_t)0;
            }
            const int u = dq ^ ((c >> 3) & 3);
            *(uint4*)&as[c][u * 8] = pack8(av);
        }
        __syncthreads();
        FragU afr[3], bfr[4];
#pragma unroll
        for (int mi = 0; mi < 3; ++mi) {
            const int row = mi * 16 + lm;
            afr[mi].u4 = *(const uint4*)&as[row][(g ^ ((row >> 3) & 3)) * 8];
        }
#pragma unroll
        for (int nj = 0; nj < 4; ++nj) {
            const int row = wvid * 64 + nj * 16 + lm;
            bfr[nj].u4 = *(const uint4*)&vs[row][(g ^ ((row >> 3) & 3)) * 8];
        }
#pragma unroll
        for (int mi = 0; mi < 3; ++mi)
#pragma unroll
            for (int nj = 0; nj < 4; ++nj)
                acc[mi][nj] = __builtin_amdgcn_mfma_f32_16x16x32_bf16(
                    afr[mi].s8, bfr[nj].s8, acc[mi][nj], 0, 0, 0);
    }

    uint16_t* ob = attn + (size_t)type * BB * DIMC * NN +
                   ((size_t)b * DIMC + (size_t)h * CHD) * NN;
    uint16_t* sw = &sw_all[wvid][0][0];
#pragma unroll
    for (int mi = 0; mi < 3; ++mi)
#pragma unroll
        for (int nj = 0; nj < 4; ++nj)
#pragma unroll
            for (int r = 0; r < 4; ++r)
                sw[(mi * 16 + g * 4 + r) * 72 + nj * 16 + lm] = f2bf(acc[mi][nj][r]);
    const int l8 = lane & 7, r8 = lane >> 3;
#pragma unroll
    for (int pass = 0; pass < 6; ++pass) {
        const int rr = pass * 8 + r8;
        uint4 v = *(const uint4*)&sw[rr * 72 + l8 * 8];
        *(uint4*)&ob[(size_t)rr * NN + n0 + wvid * 64 + l8 * 8] = v;
    }
}

extern "C" void kernel_launch(void* const* d_in, const int* in_sizes, int n_in,
                              void* d_out, int out_size, void* d_ws, size_t ws_size,
                              hipStream_t stream)
{
    const float* sar        = (const float*)d_in[0];
    const float* ms         = (const float*)d_in[1];
    const float* ms_qkv_w   = (const float*)d_in[2];
    const float* ms_qkv_b   = (const float*)d_in[3];
    const float* ms_dw_w    = (const float*)d_in[4];
    const float* ms_dw_b    = (const float*)d_in[5];
    const float* ms_temp    = (const float*)d_in[6];
    const float* sar_qkv_w  = (const float*)d_in[7];
    const float* sar_qkv_b  = (const float*)d_in[8];
    const float* sar_dw_w   = (const float*)d_in[9];
    const float* sar_dw_b   = (const float*)d_in[10];
    const float* sar_temp   = (const float*)d_in[11];
    const float* ms_proj_w  = (const float*)d_in[12];
    const float* ms_proj_b  = (const float*)d_in[13];
    const float* sar_proj_w = (const float*)d_in[14];
    const float* sar_proj_b = (const float*)d_in[15];

    char* ws = (char*)d_ws;
    // ws layout (bytes):
    //   [0,          75497472)  tmp bf16 (ms conv1x1 out) -> score partials
    //                           -> finally attn outputs (written by apply)
    //     partial: 16pid x 3type x 64ck x 2304 f32 = 28.3 MB at +0
    //     sumsq:   16pid x 64ck x 4set x 48  f32 = 0.79 MB at +32MB
    //   [75497472,  150994944)  qkv_ms bf16
    //   [150994944, 226492416)  qkv_sar bf16
    //   [230043648, 230486016)  softmaxed A f32
    //   [230486016, 231149568)  bf16 weights (wq_ms, wq_sar, wp1_ms, wp2_ms, wp_sar)
    // sar conv1x1 temp lives in d_out (fully overwritten by proj at the end).
    uint16_t* tmp     = (uint16_t*)(ws);
    uint16_t* tmp2    = (uint16_t*)(d_out);
    uint16_t* qkv_ms  = (uint16_t*)(ws + 75497472ull);
    uint16_t* qkv_sar = (uint16_t*)(ws + 150994944ull);
    float* partial    = (float*)(ws);
    float* sumsq      = (float*)(ws + 33554432ull);
    float* Amat       = (float*)(ws + 230043648ull);
    uint16_t* wq_ms   = (uint16_t*)(ws + 230486016ull);
    uint16_t* wq_sar  = (uint16_t*)(ws + 230707200ull);
    uint16_t* wp1_ms  = (uint16_t*)(ws + 230928384ull);
    uint16_t* wp2_ms  = (uint16_t*)(ws + 231002112ull);
    uint16_t* wp_sar  = (uint16_t*)(ws + 231075840ull);
    uint16_t* attn    = tmp;

    float* out_sar = (float*)d_out;
    float* out_ms  = out_sar + (size_t)BB * DIMC * NN;

    dim3 b256(256);
    k_prep<<<dim3(1152), b256, 0, stream>>>(ms_qkv_w, sar_qkv_w, ms_proj_w, sar_proj_w,
                                            wq_ms, wq_sar, wp1_ms, wp2_ms, wp_sar);
    k_conv_both<<<dim3(1024), b256, 0, stream>>>(
        ms, sar, wq_ms, wq_sar, ms_qkv_b, sar_qkv_b, tmp, tmp2);
    k_dw_both<<<dim3(2 * BB * D3 * 4), b256, 0, stream>>>(
        tmp, tmp2, ms_dw_w, sar_dw_w, ms_dw_b, sar_dw_b, qkv_ms, qkv_sar);

    k_scores_mfma<<<dim3(16 * NCK), b256, 0, stream>>>(qkv_ms, qkv_sar, partial, sumsq);
    k_softmax<<<dim3(48 * 48), dim3(64), 0, stream>>>(partial, sumsq, ms_temp, sar_temp, Amat);
    k_apply_mfma<<<dim3(48 * 64), b256, 0, stream>>>(Amat, qkv_ms, qkv_sar, attn);

    uint16_t* ms_self  = attn;
    uint16_t* sar_self = attn + (size_t)BB * DIMC * NN;
    uint16_t* crossb   = attn + 2ull * BB * DIMC * NN;
    k_proj_both<<<dim3(1024), b256, 0, stream>>>(
        sar_self, ms_self, crossb, wp_sar, wp1_ms, wp2_ms,
        sar_proj_b, ms_proj_b, sar, ms, out_sar, out_ms);
}